// Round 9
// baseline (788.426 us; speedup 1.0000x reference)
//
#include <hip/hip_runtime.h>

#define EPS 1e-5f
#define SLOPE 0.01f

typedef __attribute__((ext_vector_type(8))) short bf16x8;
typedef __attribute__((ext_vector_type(4))) float f32x4;

static __device__ __forceinline__ unsigned short f2bf(float f) {
    unsigned u = __float_as_uint(f);
    u += 0x7fff + ((u >> 16) & 1);          // round-to-nearest-even
    return (unsigned short)(u >> 16);
}
static __device__ __forceinline__ float bf2f(unsigned short h) {
    return __uint_as_float(((unsigned)h) << 16);
}

// async 16B global -> LDS (DMA, no VGPR round-trip). LDS dest = base + lane*16.
static __device__ __forceinline__ void gload16(const unsigned short* g, void* l) {
    __builtin_amdgcn_global_load_lds(
        (const __attribute__((address_space(1))) unsigned int*)g,
        (__attribute__((address_space(3))) unsigned int*)l,
        16, 0, 0);
}

// ---------------------------------------------------------------------------
// Gather-GEMM submanifold conv, bf16 MFMA 16x16x32 — r1 structure (best
// measured: 721us total, heavy convs 168us at the 1.85TB/s gather wall).
// MEASURED WALL (r0/r1/r4/r7): random 128B-line gather traffic ~260MB/heavy
// dispatch serves at 1.6-1.9 TB/s regardless of occupancy/depth/request
// size/sync scheme. r8 lesson: per-element VALU BN fusion puts ~130 VALU
// ops/chunk on the critical path (VALUBusy 10->30%, conv 168->182us).
// This version fuses BN at ZERO marginal conv cost by folding the BN scale
// into the (tiny, re-convertible) weight tables and the BN shift into a
// per-output-channel constant bias B[d] added once in the epilogue:
//   sum_c W*(x*s+h) = sum_c (W*s)*x + sum_c W*h
// Sentinel rows hold bf16(-h/s); bias_k[d] := -sum_c W'[k,c,d]*sent_c makes
// sentinel contributions cancel exactly, and B[d] = sum_k bias_k[d] is
// row-independent.
template<int K, int NCH>
__global__ __launch_bounds__(256, 3)
void conv_mfma(const unsigned short* __restrict__ in, int tableN,
               const int* __restrict__ nbr, int Nout,
               const unsigned short* __restrict__ Wt2,  // [K*NCH][2][4][64][8] bf16
               const float* __restrict__ skip,
               unsigned short* __restrict__ out_bf,
               float* __restrict__ out_f32,
               float* __restrict__ stats, int do_lrelu,
               const float* __restrict__ bias)          // B[64] or nullptr
{
    constexpr int Cin = NCH * 64;
    constexpr int KT  = K * NCH;              // 64-channel chunks

    __shared__ unsigned short Abuf[2][128 * 64];   // 2 x 16KB, rows of 128B
    __shared__ int   sIdx[K * 128];
    __shared__ float red[2][64][4];

    const int t    = threadIdx.x;
    const int lane = t & 63;
    const int w    = t >> 6;
    const int q    = lane >> 4;               // quad 0..3
    const int m    = lane & 15;
    const int row0 = blockIdx.x * 128;
    const int wrow = w * 32;                  // this wave's 32 rows

    const int glr = lane >> 3;                // gather: row-in-group 0..7
    const int gls = lane & 7;                 // gather: 16B segment 0..7

    // ---- stage all K x 128 indices (coalesced), one barrier
    for (int e = t; e < K * 128; e += 256) {
        int k = e >> 7, r = e & 127;
        int gr = row0 + r;
        sIdx[e] = (gr < Nout) ? nbr[(size_t)k * Nout + gr] : tableN;
    }
    __syncthreads();

    // per-lane bias values for its 4 output columns (L2-hit scalar loads)
    float bsv[4] = {0.f, 0.f, 0.f, 0.f};
    if (bias) {
#pragma unroll
        for (int ct = 0; ct < 4; ++ct) bsv[ct] = bias[ct * 16 + m];
    }

    f32x4 acc[2][4];
#pragma unroll
    for (int rt = 0; rt < 2; ++rt)
#pragma unroll
        for (int ct = 0; ct < 4; ++ct) acc[rt][ct] = (f32x4){0.f, 0.f, 0.f, 0.f};

    // issue this wave's 4 DMA gathers for chunk kk into buf p.
    // global source segment pre-swizzled (gls^glr): LDS row r, slot s holds
    // global segment s^(r&7); DMA dest is linear (wave-uniform base).
    auto gather = [&](int kk, int p) {
        const int k  = kk / NCH;
        const int cc = kk % NCH;
        const int* sI = &sIdx[k * 128 + wrow];
#pragma unroll
        for (int j = 0; j < 4; ++j) {
            int src = sI[j * 8 + glr];
            const unsigned short* g =
                in + (size_t)src * Cin + cc * 64 + (gls ^ glr) * 8;
            gload16(g, (void*)&Abuf[p][(wrow + j * 8) * 64]);
        }
    };
    // coalesced B-fragment load: 8 x 1KB, L2-resident
    auto loadB = [&](int kk, bf16x8 (&bb)[2][4]) {
#pragma unroll
        for (int kc = 0; kc < 2; ++kc)
#pragma unroll
            for (int ct = 0; ct < 4; ++ct)
                bb[kc][ct] = *(const bf16x8*)(
                    Wt2 + (((size_t)(kk * 2 + kc) * 4 + ct) * 64 + lane) * 8);
    };

    bf16x8 bR[2][2][4];                       // [buf][kc][ct]
    gather(0, 0);
    loadB(0, bR[0]);
    asm volatile("" ::: "memory");            // region boundary: prologue = 12 VMEM ops

#pragma unroll
    for (int kk = 0; kk < KT; ++kk) {
        const int p = kk & 1;
        if (kk + 1 < KT) {
            gather(kk + 1, p ^ 1);            // stays in flight across the wait
            loadB(kk + 1, bR[p ^ 1]);
            asm volatile("s_waitcnt vmcnt(12)" ::: "memory");
        } else {
            asm volatile("s_waitcnt vmcnt(0)" ::: "memory");
        }
        bf16x8 a[2][2];
#pragma unroll
        for (int kc = 0; kc < 2; ++kc)
#pragma unroll
            for (int rt = 0; rt < 2; ++rt)
                a[kc][rt] = *(const bf16x8*)
                    &Abuf[p][(wrow + rt * 16 + m) * 64 +
                             (((kc * 4 + q) ^ (m & 7)) * 8)];   // swizzled slot
#pragma unroll
        for (int kc = 0; kc < 2; ++kc)
#pragma unroll
            for (int rt = 0; rt < 2; ++rt)
#pragma unroll
                for (int ct = 0; ct < 4; ++ct)
                    acc[rt][ct] = __builtin_amdgcn_mfma_f32_16x16x32_bf16(
                        a[kc][rt], bR[p][kc][ct], acc[rt][ct], 0, 0, 0);
        asm volatile("" ::: "memory");        // iteration boundary
    }

    // ---- epilogue: C/D layout col=lane&15 (n), row=q*4+reg (verified m89/m91)
    float psum[4] = {0.f, 0.f, 0.f, 0.f}, psq[4] = {0.f, 0.f, 0.f, 0.f};
#pragma unroll
    for (int rt = 0; rt < 2; ++rt) {
#pragma unroll
        for (int ct = 0; ct < 4; ++ct) {
            int col = ct * 16 + m;
#pragma unroll
            for (int reg = 0; reg < 4; ++reg) {
                int r = row0 + wrow + rt * 16 + q * 4 + reg;
                if (r < Nout) {
                    float v = acc[rt][ct][reg] + bsv[ct];
                    if (skip) v += skip[(size_t)r * 64 + col];
                    if (do_lrelu) v = (v >= 0.f) ? v : SLOPE * v;
                    if (out_bf) out_bf[(size_t)r * 64 + col] = f2bf(v);
                    else        out_f32[(size_t)r * 64 + col] = v;
                    psum[ct] += v;
                    psq[ct]  += v * v;
                }
            }
        }
    }

    if (stats) {
#pragma unroll
        for (int ct = 0; ct < 4; ++ct) {
            psum[ct] += __shfl_down(psum[ct], 32);
            psum[ct] += __shfl_down(psum[ct], 16);
            psq[ct]  += __shfl_down(psq[ct], 32);
            psq[ct]  += __shfl_down(psq[ct], 16);
        }
        if (q == 0) {
#pragma unroll
            for (int ct = 0; ct < 4; ++ct) {
                red[0][ct * 16 + m][w] = psum[ct];
                red[1][ct * 16 + m][w] = psq[ct];
            }
        }
        __syncthreads();
        if (t < 64) {
            float s  = red[0][t][0] + red[0][t][1] + red[0][t][2] + red[0][t][3];
            float qq = red[1][t][0] + red[1][t][1] + red[1][t][2] + red[1][t][3];
            atomicAdd(&stats[t], s);
            atomicAdd(&stats[64 + t], qq);
        }
    }
}

// Re-convert a Cin=64 weight table with the BN scale of the producing layer
// folded in: Wt2[e] = bf16( W[k][c][d] * sc[c] ).  Layout as wt2_one (NCH=1).
__global__ __launch_bounds__(256)
void wt_scale(const float* __restrict__ W, unsigned short* __restrict__ Wt2,
              int total, const float* __restrict__ stats,
              const float* __restrict__ gamma, float invN)
{
    __shared__ float scL[64];
    int t = threadIdx.x;
    if (t < 64) {
        float mean = stats[t] * invN;
        float var  = stats[64 + t] * invN - mean * mean;
        scL[t] = gamma[t] * rsqrtf(var + EPS);
    }
    __syncthreads();
    int e = blockIdx.x * blockDim.x + t;
    if (e >= total) return;
    int j  = e & 7;
    int l  = (e >> 3) & 63;
    int ct = (e >> 9) & 3;
    int kc = (e >> 11) & 1;
    int k  = e >> 12;
    int qq = l >> 4, mm = l & 15;
    int c  = kc * 32 + qq * 8 + j;
    int d  = ct * 16 + mm;
    Wt2[e] = f2bf(W[((size_t)k * 64 + c) * 64 + d] * scL[c]);
}

// Set the producing layer's sentinel row to bf16(-sh/sc) and compute the
// folded-BN bias B[d] = -sum_{k,c} bf16(W'[k,c,d]) * sent[c] from the
// ALREADY-SCALED weight table, so sentinel gathers cancel exactly.
template<int K>
__global__ __launch_bounds__(256)
void sent_bias(unsigned short* __restrict__ tab, int tableN,
               const unsigned short* __restrict__ Wt2,
               float* __restrict__ B,
               const float* __restrict__ stats,
               const float* __restrict__ gamma,
               const float* __restrict__ beta, float invN)
{
    __shared__ float sentF[64];
    __shared__ float redB[4][64];
    int t = threadIdx.x;
    if (t < 64) {
        float mean = stats[t] * invN;
        float var  = stats[64 + t] * invN - mean * mean;
        float s    = gamma[t] * rsqrtf(var + EPS);
        float sh   = beta[t] - mean * s;
        unsigned short sv = f2bf(-sh / s);
        tab[(size_t)tableN * 64 + t] = sv;
        sentF[t] = bf2f(sv);
    }
    __syncthreads();
    int d    = t & 63;
    int part = t >> 6;                        // 4-way K split
    int ct = d >> 4, mm = d & 15;
    float s = 0.f;
    for (int k = part; k < K; k += 4) {
#pragma unroll
        for (int c = 0; c < 64; ++c) {
            int kc = c >> 5, qq = (c & 31) >> 3, j = c & 7;
            int e = ((((k * 2 + kc) * 4 + ct) * 64) + qq * 16 + mm) * 8 + j;
            s += bf2f(Wt2[e]) * sentF[c];
        }
    }
    redB[part][d] = s;
    __syncthreads();
    if (part == 0)
        B[d] = -(redB[0][d] + redB[1][d] + redB[2][d] + redB[3][d]);
}

// BN apply fp32 in-place (final layer -> d_out).
__global__ __launch_bounds__(256)
void bn_apply_f32(float* __restrict__ buf, int N,
                  const float* __restrict__ stats,
                  const float* __restrict__ gamma,
                  const float* __restrict__ beta, float invN)
{
    __shared__ float sc[64], sh[64];
    int t = threadIdx.x;
    if (t < 64) {
        float mean = stats[t] * invN;
        float var  = stats[64 + t] * invN - mean * mean;
        float s    = gamma[t] * rsqrtf(var + EPS);
        sc[t] = s;
        sh[t] = beta[t] - mean * s;
    }
    __syncthreads();
    size_t total4 = (size_t)N * 16;
    for (size_t i = (size_t)blockIdx.x * blockDim.x + t; i < total4;
         i += (size_t)gridDim.x * blockDim.x) {
        float4 v = ((const float4*)buf)[i];
        int c0 = ((int)(i & 15)) << 2;
        v.x = v.x * sc[c0]     + sh[c0];
        v.y = v.y * sc[c0 + 1] + sh[c0 + 1];
        v.z = v.z * sc[c0 + 2] + sh[c0 + 2];
        v.w = v.w * sc[c0 + 3] + sh[c0 + 3];
        ((float4*)buf)[i] = v;
    }
}

// fp32 -> bf16 elementwise convert (x_feats).
__global__ __launch_bounds__(256)
void cvt_bf16(const float* __restrict__ in, unsigned short* __restrict__ out,
              size_t n4)
{
    for (size_t i = (size_t)blockIdx.x * blockDim.x + threadIdx.x; i < n4;
         i += (size_t)gridDim.x * blockDim.x) {
        float4 v = ((const float4*)in)[i];
        ushort4 o;
        o.x = f2bf(v.x); o.y = f2bf(v.y); o.z = f2bf(v.z); o.w = f2bf(v.w);
        ((ushort4*)out)[i] = o;
    }
}

// Zero the sentinel rows (index tableN) of all gatherable feature tables.
// (tb/ab/vb sentinels are later overwritten by sent_bias; xb and ub keep
// zero sentinels — their consumers gather un-normalized data.)
__global__ __launch_bounds__(256)
void zero_sentinels(unsigned short* xb, int Nin128,
                    unsigned short* tb, int Nin64,
                    unsigned short* ub, unsigned short* ab, unsigned short* vb,
                    int Nout64)
{
    int t = threadIdx.x;
    if (t < 128) xb[(size_t)Nin128 + t] = 0;
    if (t < 64) {
        tb[(size_t)Nin64 + t] = 0;
        ub[(size_t)Nout64 + t] = 0;
        ab[(size_t)Nout64 + t] = 0;
        vb[(size_t)Nout64 + t] = 0;
    }
}

// Permute W[k][c][d] fp32 -> Wt2 bf16 with per-lane fragment layout:
// dst flat [kk][kc][ct][lane][8]; kk = k*NCH+cc; c = cc*64+kc*32+q*8+j; d = ct*16+m.
static __device__ __forceinline__ void wt2_one(int e, const float* __restrict__ W,
                                               unsigned short* __restrict__ Wt2,
                                               int NCH)
{
    int j  = e & 7;
    int l  = (e >> 3) & 63;
    int ct = (e >> 9) & 3;
    int kc = (e >> 11) & 1;
    int kk = e >> 12;
    int qq = l >> 4, mm = l & 15;
    int k  = kk / NCH, cc = kk % NCH;
    int Cin = NCH * 64;
    int c  = cc * 64 + kc * 32 + qq * 8 + j;
    int d  = ct * 16 + mm;
    Wt2[e] = f2bf(W[((size_t)k * Cin + c) * 64 + d]);
}

// Only the tables consumed UNSCALED: wt_t (trans) and wt1 (conv1).
__global__ __launch_bounds__(256)
void wt_cvt_unscaled(const float* __restrict__ W_trans,
                     const float* __restrict__ W1,
                     unsigned short* __restrict__ wt_t,
                     unsigned short* __restrict__ wt1)
{
    const int S0 = 27 * 128 * 64;            // trans (KT=54)
    const int S2 = 9 * 64 * 64;              // W1
    int e = blockIdx.x * blockDim.x + threadIdx.x;
    if (e < S0) { wt2_one(e, W_trans, wt_t, 2); return; }
    e -= S0;
    if (e < S2) { wt2_one(e, W1, wt1, 1); }
}

extern "C" void kernel_launch(void* const* d_in, const int* in_sizes, int n_in,
                              void* d_out, int out_size, void* d_ws, size_t ws_size,
                              hipStream_t stream) {
    const float* x_feats   = (const float*)d_in[0];
    const float* skip      = (const float*)d_in[1];
    const int*   nbr_trans = (const int*)d_in[2];
    const int*   nbr_up    = (const int*)d_in[3];
    const int*   nbr1      = (const int*)d_in[4];
    const int*   nbr2      = (const int*)d_in[5];
    const int*   nbr3      = (const int*)d_in[6];
    const float* W_trans   = (const float*)d_in[7];
    const float* W_up      = (const float*)d_in[8];
    const float* W1        = (const float*)d_in[9];
    const float* W2        = (const float*)d_in[10];
    const float* W3        = (const float*)d_in[11];
    const float* gamma_t   = (const float*)d_in[12];
    const float* beta_t    = (const float*)d_in[13];
    const float* gamma1    = (const float*)d_in[14];
    const float* beta1     = (const float*)d_in[15];
    const float* gamma2    = (const float*)d_in[16];
    const float* beta2     = (const float*)d_in[17];
    const float* gamma3    = (const float*)d_in[18];
    const float* beta3     = (const float*)d_in[19];

    const int Nin  = in_sizes[0] / 128;   // 80000
    const int Nout = in_sizes[1] / 64;    // 200000

    size_t off = 0;
    auto alloc = [&](size_t bytes) {
        void* p = (char*)d_ws + off;
        off = (off + bytes + 255) & ~(size_t)255;
        return p;
    };
    unsigned short* xb   = (unsigned short*)alloc(((size_t)Nin + 1) * 128 * 2);
    unsigned short* tb   = (unsigned short*)alloc(((size_t)Nin + 1) * 64 * 2);
    unsigned short* ub   = (unsigned short*)alloc(((size_t)Nout + 1) * 64 * 2);
    unsigned short* ab   = (unsigned short*)alloc(((size_t)Nout + 1) * 64 * 2);
    unsigned short* vb   = (unsigned short*)alloc(((size_t)Nout + 1) * 64 * 2);
    unsigned short* wt_t = (unsigned short*)alloc((size_t)27 * 128 * 64 * 2);
    unsigned short* wt_u = (unsigned short*)alloc((size_t)27 * 64 * 64 * 2);
    unsigned short* wt1  = (unsigned short*)alloc((size_t)9 * 64 * 64 * 2);
    unsigned short* wt2  = (unsigned short*)alloc((size_t)9 * 64 * 64 * 2);
    unsigned short* wt3  = (unsigned short*)alloc((size_t)27 * 64 * 64 * 2);
    float* stats = (float*)alloc(512 * sizeof(float));
    float* biasB = (float*)alloc(192 * sizeof(float));
    float* out   = (float*)d_out;

    hipMemsetAsync(stats, 0, 512 * sizeof(float), stream);

    dim3 blk(256);
    const float invNin  = 1.f / (float)Nin;
    const float invNout = 1.f / (float)Nout;

    wt_cvt_unscaled<<<1008, blk, 0, stream>>>(W_trans, W1, wt_t, wt1);
    cvt_bf16<<<2048, blk, 0, stream>>>(x_feats, xb, (size_t)Nin * 32);
    zero_sentinels<<<1, blk, 0, stream>>>(xb, Nin * 128, tb, Nin * 64,
                                          ub, ab, vb, Nout * 64);

    const int gIn  = (Nin  + 127) / 128;  // 625
    const int gOut = (Nout + 127) / 128;  // 1563
    const int W27  = 27 * 64 * 64;        // 110592
    const int W9   = 9 * 64 * 64;         // 36864

    // trans_dilao: Cin=128, K=27 + LeakyReLU -> tb raw; stats_t accumulated
    conv_mfma<27, 2><<<gIn, blk, 0, stream>>>(
        xb, Nin, nbr_trans, Nin, wt_t, nullptr, tb, nullptr, stats + 0, 1,
        nullptr);
    // fold BN_t into up-conv: scale wt_u, set tb sentinel, compute B_u
    wt_scale<<<(W27 + 255) / 256, blk, 0, stream>>>(
        W_up, wt_u, W27, stats + 0, gamma_t, invNin);
    sent_bias<27><<<1, blk, 0, stream>>>(tb, Nin, wt_u, biasB + 0,
                                         stats + 0, gamma_t, beta_t, invNin);
    // SparseInverseConv K=27 + skip (no act/bn); BN_t folded in weights/bias
    conv_mfma<27, 1><<<gOut, blk, 0, stream>>>(
        tb, Nin, nbr_up, Nout, wt_u, skip, ub, nullptr, nullptr, 0,
        biasB + 0);
    // conv1 K=9 + LeakyReLU; raw ub input (no BN) -> ab raw; stats1
    conv_mfma<9, 1><<<gOut, blk, 0, stream>>>(
        ub, Nout, nbr1, Nout, wt1, nullptr, ab, nullptr, stats + 128, 1,
        nullptr);
    // fold BN1 into conv2
    wt_scale<<<(W9 + 255) / 256, blk, 0, stream>>>(
        W2, wt2, W9, stats + 128, gamma1, invNout);
    sent_bias<9><<<1, blk, 0, stream>>>(ab, Nout, wt2, biasB + 64,
                                        stats + 128, gamma1, beta1, invNout);
    // conv2 K=9 + LeakyReLU; BN1 folded -> vb raw; stats2
    conv_mfma<9, 1><<<gOut, blk, 0, stream>>>(
        ab, Nout, nbr2, Nout, wt2, nullptr, vb, nullptr, stats + 256, 1,
        biasB + 64);
    // fold BN2 into conv3
    wt_scale<<<(W27 + 255) / 256, blk, 0, stream>>>(
        W3, wt3, W27, stats + 256, gamma2, invNout);
    sent_bias<27><<<1, blk, 0, stream>>>(vb, Nout, wt3, biasB + 128,
                                         stats + 256, gamma2, beta2, invNout);
    // conv3 K=27 + LeakyReLU; BN2 folded -> d_out fp32; stats3; BN3 in place
    conv_mfma<27, 1><<<gOut, blk, 0, stream>>>(
        vb, Nout, nbr3, Nout, wt3, nullptr, nullptr, out, stats + 384, 1,
        biasB + 128);
    bn_apply_f32<<<2048, blk, 0, stream>>>(out, Nout, stats + 384,
                                           gamma3, beta3, invNout);
}

// Round 11
// 718.565 us; speedup vs baseline: 1.0972x; 1.0972x over previous
//
#include <hip/hip_runtime.h>

#define EPS 1e-5f
#define SLOPE 0.01f

typedef __attribute__((ext_vector_type(8))) short bf16x8;
typedef __attribute__((ext_vector_type(4))) float f32x4;

static __device__ __forceinline__ unsigned short f2bf(float f) {
    unsigned u = __float_as_uint(f);
    u += 0x7fff + ((u >> 16) & 1);          // round-to-nearest-even
    return (unsigned short)(u >> 16);
}
static __device__ __forceinline__ float bf2f(unsigned short h) {
    return __uint_as_float(((unsigned)h) << 16);
}

// async 16B global -> LDS (DMA, no VGPR round-trip). LDS dest = base + lane*16.
static __device__ __forceinline__ void gload16(const unsigned short* g, void* l) {
    __builtin_amdgcn_global_load_lds(
        (const __attribute__((address_space(1))) unsigned int*)g,
        (__attribute__((address_space(3))) unsigned int*)l,
        16, 0, 0);
}

// ---------------------------------------------------------------------------
// Gather-GEMM submanifold conv, bf16 MFMA 16x16x32 — r1 structure (best
// measured: heavy convs ~168us at the 1.85TB/s random-gather wall).
// MEASURED WALL (r0/r1/r4/r7/r9): L2-miss line traffic ~260MB/heavy dispatch,
// service 1.6-1.9 TB/s, invariant across sync scheme, request shape,
// occupancy 27-53%, staging path. BN is folded into weights+bias (r9, zero
// marginal conv cost): sum_c W*(x*s+h) = sum_c (W*s)*x + B. Sentinel rows
// hold bf16(-h/s) so sentinel gathers cancel against B exactly.
// r9 lesson: the fold kernels must be PARALLEL — single-block sent_bias cost
// ~25us x3 serialized; r10 merges scale+sentinel+bias into one wide kernel.
template<int K, int NCH>
__global__ __launch_bounds__(256, 3)
void conv_mfma(const unsigned short* __restrict__ in, int tableN,
               const int* __restrict__ nbr, int Nout,
               const unsigned short* __restrict__ Wt2,  // [K*NCH][2][4][64][8] bf16
               const float* __restrict__ skip,
               unsigned short* __restrict__ out_bf,
               float* __restrict__ out_f32,
               float* __restrict__ stats, int do_lrelu,
               const float* __restrict__ bias)          // B[64] or nullptr
{
    constexpr int Cin = NCH * 64;
    constexpr int KT  = K * NCH;              // 64-channel chunks

    __shared__ unsigned short Abuf[2][128 * 64];   // 2 x 16KB, rows of 128B
    __shared__ int   sIdx[K * 128];
    __shared__ float red[2][64][4];

    const int t    = threadIdx.x;
    const int lane = t & 63;
    const int w    = t >> 6;
    const int q    = lane >> 4;               // quad 0..3
    const int m    = lane & 15;
    const int row0 = blockIdx.x * 128;
    const int wrow = w * 32;                  // this wave's 32 rows

    const int glr = lane >> 3;                // gather: row-in-group 0..7
    const int gls = lane & 7;                 // gather: 16B segment 0..7

    // ---- stage all K x 128 indices (coalesced), one barrier
    for (int e = t; e < K * 128; e += 256) {
        int k = e >> 7, r = e & 127;
        int gr = row0 + r;
        sIdx[e] = (gr < Nout) ? nbr[(size_t)k * Nout + gr] : tableN;
    }
    __syncthreads();

    // per-lane bias values for its 4 output columns (L2-hit scalar loads)
    float bsv[4] = {0.f, 0.f, 0.f, 0.f};
    if (bias) {
#pragma unroll
        for (int ct = 0; ct < 4; ++ct) bsv[ct] = bias[ct * 16 + m];
    }

    f32x4 acc[2][4];
#pragma unroll
    for (int rt = 0; rt < 2; ++rt)
#pragma unroll
        for (int ct = 0; ct < 4; ++ct) acc[rt][ct] = (f32x4){0.f, 0.f, 0.f, 0.f};

    // issue this wave's 4 DMA gathers for chunk kk into buf p.
    // global source segment pre-swizzled (gls^glr): LDS row r, slot s holds
    // global segment s^(r&7); DMA dest is linear (wave-uniform base).
    auto gather = [&](int kk, int p) {
        const int k  = kk / NCH;
        const int cc = kk % NCH;
        const int* sI = &sIdx[k * 128 + wrow];
#pragma unroll
        for (int j = 0; j < 4; ++j) {
            int src = sI[j * 8 + glr];
            const unsigned short* g =
                in + (size_t)src * Cin + cc * 64 + (gls ^ glr) * 8;
            gload16(g, (void*)&Abuf[p][(wrow + j * 8) * 64]);
        }
    };
    // coalesced B-fragment load: 8 x 1KB, L2-resident
    auto loadB = [&](int kk, bf16x8 (&bb)[2][4]) {
#pragma unroll
        for (int kc = 0; kc < 2; ++kc)
#pragma unroll
            for (int ct = 0; ct < 4; ++ct)
                bb[kc][ct] = *(const bf16x8*)(
                    Wt2 + (((size_t)(kk * 2 + kc) * 4 + ct) * 64 + lane) * 8);
    };

    bf16x8 bR[2][2][4];                       // [buf][kc][ct]
    gather(0, 0);
    loadB(0, bR[0]);
    asm volatile("" ::: "memory");            // region boundary: prologue = 12 VMEM ops

#pragma unroll
    for (int kk = 0; kk < KT; ++kk) {
        const int p = kk & 1;
        if (kk + 1 < KT) {
            gather(kk + 1, p ^ 1);            // stays in flight across the wait
            loadB(kk + 1, bR[p ^ 1]);
            asm volatile("s_waitcnt vmcnt(12)" ::: "memory");
        } else {
            asm volatile("s_waitcnt vmcnt(0)" ::: "memory");
        }
        bf16x8 a[2][2];
#pragma unroll
        for (int kc = 0; kc < 2; ++kc)
#pragma unroll
            for (int rt = 0; rt < 2; ++rt)
                a[kc][rt] = *(const bf16x8*)
                    &Abuf[p][(wrow + rt * 16 + m) * 64 +
                             (((kc * 4 + q) ^ (m & 7)) * 8)];   // swizzled slot
#pragma unroll
        for (int kc = 0; kc < 2; ++kc)
#pragma unroll
            for (int rt = 0; rt < 2; ++rt)
#pragma unroll
                for (int ct = 0; ct < 4; ++ct)
                    acc[rt][ct] = __builtin_amdgcn_mfma_f32_16x16x32_bf16(
                        a[kc][rt], bR[p][kc][ct], acc[rt][ct], 0, 0, 0);
        asm volatile("" ::: "memory");        // iteration boundary
    }

    // ---- epilogue: C/D layout col=lane&15 (n), row=q*4+reg (verified m89/m91)
    float psum[4] = {0.f, 0.f, 0.f, 0.f}, psq[4] = {0.f, 0.f, 0.f, 0.f};
#pragma unroll
    for (int rt = 0; rt < 2; ++rt) {
#pragma unroll
        for (int ct = 0; ct < 4; ++ct) {
            int col = ct * 16 + m;
#pragma unroll
            for (int reg = 0; reg < 4; ++reg) {
                int r = row0 + wrow + rt * 16 + q * 4 + reg;
                if (r < Nout) {
                    float v = acc[rt][ct][reg] + bsv[ct];
                    if (skip) v += skip[(size_t)r * 64 + col];
                    if (do_lrelu) v = (v >= 0.f) ? v : SLOPE * v;
                    if (out_bf) out_bf[(size_t)r * 64 + col] = f2bf(v);
                    else        out_f32[(size_t)r * 64 + col] = v;
                    psum[ct] += v;
                    psq[ct]  += v * v;
                }
            }
        }
    }

    if (stats) {
#pragma unroll
        for (int ct = 0; ct < 4; ++ct) {
            psum[ct] += __shfl_down(psum[ct], 32);
            psum[ct] += __shfl_down(psum[ct], 16);
            psq[ct]  += __shfl_down(psq[ct], 32);
            psq[ct]  += __shfl_down(psq[ct], 16);
        }
        if (q == 0) {
#pragma unroll
            for (int ct = 0; ct < 4; ++ct) {
                red[0][ct * 16 + m][w] = psum[ct];
                red[1][ct * 16 + m][w] = psq[ct];
            }
        }
        __syncthreads();
        if (t < 64) {
            float s  = red[0][t][0] + red[0][t][1] + red[0][t][2] + red[0][t][3];
            float qq = red[1][t][0] + red[1][t][1] + red[1][t][2] + red[1][t][3];
            atomicAdd(&stats[t], s);
            atomicAdd(&stats[64 + t], qq);
        }
    }
}

// ---------------------------------------------------------------------------
// PARALLEL BN-fold (r10): one wide kernel does all three fold steps:
//   Wt2[e]  = bf16( W[k][c][d] * sc[c] )      (scaled weight table)
//   tab sentinel row <- bf16(-sh/sc)          (block 0)
//   B[d]    = -sum_{k,c} bf16(W') * sent[c]   (block-reduced atomicAdd)
// Grid = K*16 blocks x 256. B must be pre-zeroed.
// Per-block invariants of the e-layout: ct constant, mm = (t>>3)&15.
template<int K>
__global__ __launch_bounds__(256)
void wt_scale_bias(const float* __restrict__ W, unsigned short* __restrict__ Wt2,
                   unsigned short* __restrict__ tab, int tableN,
                   float* __restrict__ B,
                   const float* __restrict__ stats,
                   const float* __restrict__ gamma,
                   const float* __restrict__ beta, float invN)
{
    __shared__ float scL[64], sentL[64];
    __shared__ float redD[16];
    const int t = threadIdx.x;
    if (t < 64) {
        float mean = stats[t] * invN;
        float var  = stats[64 + t] * invN - mean * mean;
        float s    = gamma[t] * rsqrtf(var + EPS);
        float sh   = beta[t] - mean * s;
        unsigned short sv = f2bf(-sh / s);
        scL[t]   = s;
        sentL[t] = bf2f(sv);
        if (blockIdx.x == 0) tab[(size_t)tableN * 64 + t] = sv;
    }
    if (t < 16) redD[t] = 0.f;
    __syncthreads();

    const int e  = blockIdx.x * 256 + t;      // e < K*4096, grid sized exactly
    const int j  = e & 7;
    const int l  = (e >> 3) & 63;
    const int ct = (e >> 9) & 3;              // constant within a block
    const int kc = (e >> 11) & 1;
    const int k  = e >> 12;
    const int qq = l >> 4, mm = l & 15;
    const int c  = kc * 32 + qq * 8 + j;
    const int d  = ct * 16 + mm;

    unsigned short wv = f2bf(W[((size_t)k * 64 + c) * 64 + d] * scL[c]);
    Wt2[e] = wv;
    float p = bf2f(wv) * sentL[c];

    // reduce the 8 j-lanes (consecutive lanes sharing t>>3) then LDS-combine
    p += __shfl_down(p, 4);
    p += __shfl_down(p, 2);
    p += __shfl_down(p, 1);
    if ((t & 7) == 0) atomicAdd(&redD[(t >> 3) & 15], p);
    __syncthreads();
    if (t < 16) atomicAdd(&B[ct * 16 + t], -redD[t]);
}

// BN apply fp32 in-place (final layer -> d_out).
__global__ __launch_bounds__(256)
void bn_apply_f32(float* __restrict__ buf, int N,
                  const float* __restrict__ stats,
                  const float* __restrict__ gamma,
                  const float* __restrict__ beta, float invN)
{
    __shared__ float sc[64], sh[64];
    int t = threadIdx.x;
    if (t < 64) {
        float mean = stats[t] * invN;
        float var  = stats[64 + t] * invN - mean * mean;
        float s    = gamma[t] * rsqrtf(var + EPS);
        sc[t] = s;
        sh[t] = beta[t] - mean * s;
    }
    __syncthreads();
    size_t total4 = (size_t)N * 16;
    for (size_t i = (size_t)blockIdx.x * blockDim.x + t; i < total4;
         i += (size_t)gridDim.x * blockDim.x) {
        float4 v = ((const float4*)buf)[i];
        int c0 = ((int)(i & 15)) << 2;
        v.x = v.x * sc[c0]     + sh[c0];
        v.y = v.y * sc[c0 + 1] + sh[c0 + 1];
        v.z = v.z * sc[c0 + 2] + sh[c0 + 2];
        v.w = v.w * sc[c0 + 3] + sh[c0 + 3];
        ((float4*)buf)[i] = v;
    }
}

// fp32 -> bf16 elementwise convert (x_feats).
__global__ __launch_bounds__(256)
void cvt_bf16(const float* __restrict__ in, unsigned short* __restrict__ out,
              size_t n4)
{
    for (size_t i = (size_t)blockIdx.x * blockDim.x + threadIdx.x; i < n4;
         i += (size_t)gridDim.x * blockDim.x) {
        float4 v = ((const float4*)in)[i];
        ushort4 o;
        o.x = f2bf(v.x); o.y = f2bf(v.y); o.z = f2bf(v.z); o.w = f2bf(v.w);
        ((ushort4*)out)[i] = o;
    }
}

// Zero the sentinel rows (index tableN) of all gatherable feature tables.
// (tb/ab/vb sentinels are later overwritten by wt_scale_bias; xb and ub keep
// zero sentinels — their consumers gather un-normalized data.)
__global__ __launch_bounds__(256)
void zero_sentinels(unsigned short* xb, int Nin128,
                    unsigned short* tb, int Nin64,
                    unsigned short* ub, unsigned short* ab, unsigned short* vb,
                    int Nout64)
{
    int t = threadIdx.x;
    if (t < 128) xb[(size_t)Nin128 + t] = 0;
    if (t < 64) {
        tb[(size_t)Nin64 + t] = 0;
        ub[(size_t)Nout64 + t] = 0;
        ab[(size_t)Nout64 + t] = 0;
        vb[(size_t)Nout64 + t] = 0;
    }
}

// Permute W[k][c][d] fp32 -> Wt2 bf16 with per-lane fragment layout:
// dst flat [kk][kc][ct][lane][8]; kk = k*NCH+cc; c = cc*64+kc*32+q*8+j; d = ct*16+m.
static __device__ __forceinline__ void wt2_one(int e, const float* __restrict__ W,
                                               unsigned short* __restrict__ Wt2,
                                               int NCH)
{
    int j  = e & 7;
    int l  = (e >> 3) & 63;
    int ct = (e >> 9) & 3;
    int kc = (e >> 11) & 1;
    int kk = e >> 12;
    int qq = l >> 4, mm = l & 15;
    int k  = kk / NCH, cc = kk % NCH;
    int Cin = NCH * 64;
    int c  = cc * 64 + kc * 32 + qq * 8 + j;
    int d  = ct * 16 + mm;
    Wt2[e] = f2bf(W[((size_t)k * Cin + c) * 64 + d]);
}

// Only the tables consumed UNSCALED: wt_t (trans) and wt1 (conv1).
__global__ __launch_bounds__(256)
void wt_cvt_unscaled(const float* __restrict__ W_trans,
                     const float* __restrict__ W1,
                     unsigned short* __restrict__ wt_t,
                     unsigned short* __restrict__ wt1)
{
    const int S0 = 27 * 128 * 64;            // trans (KT=54)
    const int S2 = 9 * 64 * 64;              // W1
    int e = blockIdx.x * blockDim.x + threadIdx.x;
    if (e < S0) { wt2_one(e, W_trans, wt_t, 2); return; }
    e -= S0;
    if (e < S2) { wt2_one(e, W1, wt1, 1); }
}

extern "C" void kernel_launch(void* const* d_in, const int* in_sizes, int n_in,
                              void* d_out, int out_size, void* d_ws, size_t ws_size,
                              hipStream_t stream) {
    const float* x_feats   = (const float*)d_in[0];
    const float* skip      = (const float*)d_in[1];
    const int*   nbr_trans = (const int*)d_in[2];
    const int*   nbr_up    = (const int*)d_in[3];
    const int*   nbr1      = (const int*)d_in[4];
    const int*   nbr2      = (const int*)d_in[5];
    const int*   nbr3      = (const int*)d_in[6];
    const float* W_trans   = (const float*)d_in[7];
    const float* W_up      = (const float*)d_in[8];
    const float* W1        = (const float*)d_in[9];
    const float* W2        = (const float*)d_in[10];
    const float* W3        = (const float*)d_in[11];
    const float* gamma_t   = (const float*)d_in[12];
    const float* beta_t    = (const float*)d_in[13];
    const float* gamma1    = (const float*)d_in[14];
    const float* beta1     = (const float*)d_in[15];
    const float* gamma2    = (const float*)d_in[16];
    const float* beta2     = (const float*)d_in[17];
    const float* gamma3    = (const float*)d_in[18];
    const float* beta3     = (const float*)d_in[19];

    const int Nin  = in_sizes[0] / 128;   // 80000
    const int Nout = in_sizes[1] / 64;    // 200000

    size_t off = 0;
    auto alloc = [&](size_t bytes) {
        void* p = (char*)d_ws + off;
        off = (off + bytes + 255) & ~(size_t)255;
        return p;
    };
    unsigned short* xb   = (unsigned short*)alloc(((size_t)Nin + 1) * 128 * 2);
    unsigned short* tb   = (unsigned short*)alloc(((size_t)Nin + 1) * 64 * 2);
    unsigned short* ub   = (unsigned short*)alloc(((size_t)Nout + 1) * 64 * 2);
    unsigned short* ab   = (unsigned short*)alloc(((size_t)Nout + 1) * 64 * 2);
    unsigned short* vb   = (unsigned short*)alloc(((size_t)Nout + 1) * 64 * 2);
    unsigned short* wt_t = (unsigned short*)alloc((size_t)27 * 128 * 64 * 2);
    unsigned short* wt_u = (unsigned short*)alloc((size_t)27 * 64 * 64 * 2);
    unsigned short* wt1  = (unsigned short*)alloc((size_t)9 * 64 * 64 * 2);
    unsigned short* wt2  = (unsigned short*)alloc((size_t)9 * 64 * 64 * 2);
    unsigned short* wt3  = (unsigned short*)alloc((size_t)27 * 64 * 64 * 2);
    float* stats = (float*)alloc(512 * sizeof(float));   // 2048B, 256-aligned
    float* biasB = (float*)alloc(192 * sizeof(float));   // contiguous after stats
    float* out   = (float*)d_out;

    // zero stats (512 f) + biasB (192 f) in one contiguous memset
    hipMemsetAsync(stats, 0, 704 * sizeof(float), stream);

    dim3 blk(256);
    const float invNin  = 1.f / (float)Nin;
    const float invNout = 1.f / (float)Nout;

    wt_cvt_unscaled<<<1008, blk, 0, stream>>>(W_trans, W1, wt_t, wt1);
    cvt_bf16<<<2048, blk, 0, stream>>>(x_feats, xb, (size_t)Nin * 32);
    zero_sentinels<<<1, blk, 0, stream>>>(xb, Nin * 128, tb, Nin * 64,
                                          ub, ab, vb, Nout * 64);

    const int gIn  = (Nin  + 127) / 128;  // 625
    const int gOut = (Nout + 127) / 128;  // 1563

    // trans_dilao: Cin=128, K=27 + LeakyReLU -> tb raw; stats_t accumulated
    conv_mfma<27, 2><<<gIn, blk, 0, stream>>>(
        xb, Nin, nbr_trans, Nin, wt_t, nullptr, tb, nullptr, stats + 0, 1,
        nullptr);
    // fold BN_t into up-conv (parallel): scale wt_u, tb sentinel, bias B_u
    wt_scale_bias<27><<<27 * 16, blk, 0, stream>>>(
        W_up, wt_u, tb, Nin, biasB + 0, stats + 0, gamma_t, beta_t, invNin);
    // SparseInverseConv K=27 + skip (no act/bn); BN_t folded in weights/bias
    conv_mfma<27, 1><<<gOut, blk, 0, stream>>>(
        tb, Nin, nbr_up, Nout, wt_u, skip, ub, nullptr, nullptr, 0,
        biasB + 0);
    // conv1 K=9 + LeakyReLU; raw ub input (no BN) -> ab raw; stats1
    conv_mfma<9, 1><<<gOut, blk, 0, stream>>>(
        ub, Nout, nbr1, Nout, wt1, nullptr, ab, nullptr, stats + 128, 1,
        nullptr);
    // fold BN1 into conv2
    wt_scale_bias<9><<<9 * 16, blk, 0, stream>>>(
        W2, wt2, ab, Nout, biasB + 64, stats + 128, gamma1, beta1, invNout);
    // conv2 K=9 + LeakyReLU; BN1 folded -> vb raw; stats2
    conv_mfma<9, 1><<<gOut, blk, 0, stream>>>(
        ab, Nout, nbr2, Nout, wt2, nullptr, vb, nullptr, stats + 256, 1,
        biasB + 64);
    // fold BN2 into conv3
    wt_scale_bias<27><<<27 * 16, blk, 0, stream>>>(
        W3, wt3, vb, Nout, biasB + 128, stats + 256, gamma2, beta2, invNout);
    // conv3 K=27 + LeakyReLU; BN2 folded -> d_out fp32; stats3; BN3 in place
    conv_mfma<27, 1><<<gOut, blk, 0, stream>>>(
        vb, Nout, nbr3, Nout, wt3, nullptr, nullptr, out, stats + 384, 1,
        biasB + 128);
    bn_apply_f32<<<2048, blk, 0, stream>>>(out, Nout, stats + 384,
                                           gamma3, beta3, invNout);
}